// Round 10
// baseline (849.362 us; speedup 1.0000x reference)
//
#include <hip/hip_runtime.h>
#include <hip/hip_bf16.h>

#define LEAK 0.2f

__device__ __forceinline__ float lrelu(float a) { return a > 0.0f ? a : LEAK * a; }

// ---------------------------------------------------------------------------
// Implicit-GEMM conv + leaky ReLU.  out[co][pix] = sum_k wT[k][co]*B[k][pix]
// Micro-tile MR co x NR px. Double-buffered LDS, one barrier per BK-k step.
// NR==8: B stored with even/odd float4-group split (conflict-free reads).
// NTHR = block size; BK = K-step (16 or 32).
// ---------------------------------------------------------------------------
template<int CI, int ST, int KH, int KW, int KIN, int KP,
         int PIH, int PIW, int LP, int OW, int PPI,
         int CO, int NT, int MR, int NR, int OSH, int OSW, int OR0, int OC0,
         int MINW, int NTHR, int BK>
__global__ __launch_bounds__(NTHR, MINW) void conv_gemm_k(
    const float* __restrict__ in,    // padded input [img*CI + ci][PIH][PIW]
    const float* __restrict__ wT,    // [KP][CO]
    const float* __restrict__ bias,
    float* __restrict__ out)
{
    constexpr int KT  = KP / BK;
    constexpr int TXW = NT / 4;         // B staging pixel-quads per k-row
    constexpr int TXN = NT / NR;        // compute columns
    constexpr int BT  = BK * NT / 4;
    constexpr int AT  = BK * CO / 4;
    constexpr int BI  = (BT + NTHR - 1) / NTHR;
    constexpr int AI  = (AT + NTHR - 1) / NTHR;
    constexpr int ASZ = BK * CO;
    constexpr int BSZ = BK * NT;

    __shared__ float sm[2 * ASZ + 2 * BSZ];

    const int tid = threadIdx.x;
    const int bx  = blockIdx.x;
    const int tx  = tid % TXN;
    const int ty  = tid / TXN;

    // ---- per-thread staging geometry (K-independent) ----
    int bofs[BI], bkl[BI], bcol[BI];
#pragma unroll
    for (int q = 0; q < BI; ++q) {
        int task = tid + q * NTHR;
        if ((BT % NTHR == 0) || task < BT) {
            int kl  = task / TXW;
            int pxq = task % TXW;
            int px0 = bx * NT + pxq * 4;
            int img = px0 / PPI;
            int n   = px0 % PPI;
            int oh  = n / OW, ow = n % OW;
            bofs[q] = ((img * CI) * PIH + oh * ST) * PIW + ow * ST + LP;
            bkl[q]  = kl;
            // even/odd group split for NR==8 (conflict-free 8-wide reads)
            bcol[q] = (NR == 8) ? (((pxq & 1) * (TXW / 2) + (pxq >> 1)) * 4)
                                : (pxq * 4);
        }
    }

    float  br[BI][4];
    float4 ar[AI];

    auto gather = [&](int it) {
        int k0 = it * BK;
#pragma unroll
        for (int q = 0; q < BI; ++q) {
            int task = tid + q * NTHR;
            if ((BT % NTHR == 0) || task < BT) {
                int k = k0 + bkl[q];
                if (KP > KIN) k = min(k, KIN - 1);   // padded-K tail (weights 0)
                int ci  = k / (KH * KW);
                int rem = k - ci * (KH * KW);
                int kh  = rem / KW;
                int kw  = rem - kh * KW;
                const float* __restrict__ s = in + bofs[q] + (ci * PIH + kh) * PIW + kw;
                br[q][0] = s[0]; br[q][1] = s[ST]; br[q][2] = s[2 * ST]; br[q][3] = s[3 * ST];
            }
        }
#pragma unroll
        for (int p = 0; p < AI; ++p) {
            int task = tid + p * NTHR;
            if ((AT % NTHR == 0) || task < AT)
                ar[p] = *(const float4*)&wT[(size_t)k0 * CO + task * 4];
        }
    };

    float acc[MR][NR];
#pragma unroll
    for (int j = 0; j < MR; ++j) {
        float bv = bias[ty * MR + j];
#pragma unroll
        for (int i = 0; i < NR; ++i) acc[j][i] = bv;
    }

    gather(0);
    for (int it = 0; it < KT; ++it) {
        const int p = it & 1;
        float* __restrict__ Asb = sm + p * ASZ;
        float* __restrict__ Bsb = sm + 2 * ASZ + p * BSZ;
#pragma unroll
        for (int pa = 0; pa < AI; ++pa) {
            int task = tid + pa * NTHR;
            if ((AT % NTHR == 0) || task < AT)
                *(float4*)&Asb[task * 4] = ar[pa];
        }
#pragma unroll
        for (int q = 0; q < BI; ++q) {
            int task = tid + q * NTHR;
            if ((BT % NTHR == 0) || task < BT)
                *(float4*)&Bsb[bkl[q] * NT + bcol[q]] =
                    make_float4(br[q][0], br[q][1], br[q][2], br[q][3]);
        }
        __syncthreads();
        if (it + 1 < KT) gather(it + 1);
#pragma unroll
        for (int k = 0; k < BK; ++k) {
            float b[NR], a[MR];
            if (NR == 8) {
                // split layout: logical groups {2tx, 2tx+1} at {tx, NT/8+tx}
                *(float4*)&b[0] = *(const float4*)&Bsb[k * NT + tx * 4];
                *(float4*)&b[4] = *(const float4*)&Bsb[k * NT + NT / 2 + tx * 4];
            } else {
#pragma unroll
                for (int i = 0; i < NR / 4; ++i)
                    *(float4*)&b[4 * i] = *(const float4*)&Bsb[k * NT + tx * NR + 4 * i];
            }
#pragma unroll
            for (int j = 0; j < MR / 4; ++j)
                *(float4*)&a[4 * j] = *(const float4*)&Asb[k * CO + ty * MR + 4 * j];
#pragma unroll
            for (int j = 0; j < MR; ++j)
#pragma unroll
                for (int i = 0; i < NR; ++i)
                    acc[j][i] += a[j] * b[i];
        }
    }

    // ---- store (NR consecutive px share one row; OC0/ow 4-aligned) ----
    {
        int pxs = bx * NT + tx * NR;
        int img = pxs / PPI;
        int n   = pxs % PPI;
        int oh  = n / OW, ow = n % OW;
#pragma unroll
        for (int j = 0; j < MR; ++j) {
            int co = ty * MR + j;
            size_t off = (((size_t)img * CO + co) * OSH + (oh + OR0)) * OSW + (ow + OC0);
#pragma unroll
            for (int q = 0; q < NR / 4; ++q) {
                float4 v = make_float4(lrelu(acc[j][4 * q + 0]), lrelu(acc[j][4 * q + 1]),
                                       lrelu(acc[j][4 * q + 2]), lrelu(acc[j][4 * q + 3]));
                *(float4*)&out[off + 4 * q] = v;
            }
        }
    }
}

// ---------------------------------------------------------------------------
// Weight transpose: wT[k][co] = w[co][k], K padded to KP with zeros.
// ---------------------------------------------------------------------------
template<int CO, int KIN, int KP>
__global__ __launch_bounds__(256) void wtr_k(const float* __restrict__ w,
                                             float* __restrict__ wT) {
    int i = blockIdx.x * 256 + threadIdx.x;
    if (i >= KP * CO) return;
    int k = i / CO, co = i % CO;
    wT[i] = (k < KIN) ? w[(size_t)co * KIN + k] : 0.0f;
}

// ---------------------------------------------------------------------------
// x -> x_pad [32*3][228][228], 2-pixel zero border.
// ---------------------------------------------------------------------------
__global__ __launch_bounds__(256) void pad_x_k(const float* __restrict__ x,
                                               float* __restrict__ xp) {
    int blk = blockIdx.x;              // 32*3*57
    int r4 = blk % 57, ic = blk / 57;
    int wid = threadIdx.x >> 6, lane = threadIdx.x & 63;
    int row = r4 * 4 + wid;
    const float* __restrict__ src = x + (size_t)ic * 224 * 224 + (size_t)(row - 2) * 224;
    float* __restrict__ dst = xp + (size_t)ic * 228 * 228 + (size_t)row * 228;
    bool rok = (row >= 2) && (row < 226);
    for (int c = lane; c < 228; c += 64) {
        float v = 0.0f;
        if (rok && c >= 2 && c < 226) v = src[c - 2];
        dst[c] = v;
    }
}

// c1p plane = 116 x 120; data ow at layout col ow+4 (border cols 2,3,116,117).
__global__ __launch_bounds__(256) void zb_c1p_k(float* __restrict__ p) {
    float* base = p + (size_t)blockIdx.x * (116 * 120);
    for (int t = threadIdx.x; t < 928; t += 256) {
        int idx;
        if (t < 480) {
            int r = t / 120, c = t - r * 120;
            int row = (r < 2) ? r : r + 112;
            idx = row * 120 + c;
        } else {
            int s = t - 480;
            int r = s >> 2, c = s & 3;
            int col = (c < 2) ? (c + 2) : (c + 114);
            idx = (r + 2) * 120 + col;
        }
        base[idx] = 0.0f;
    }
}

// c2p plane = 58 x 64; data ow at layout col ow+4 (border cols 3,60).
__global__ __launch_bounds__(64) void zb_c2p_k(float* __restrict__ p) {
    float* base = p + (size_t)blockIdx.x * (58 * 64);
    for (int t = threadIdx.x; t < 240; t += 64) {
        int idx;
        if (t < 128) {
            int r = t >> 6, c = t & 63;
            idx = (r ? 57 : 0) * 64 + c;
        } else {
            int s = t - 128;
            int r = (s >> 1) + 1;
            idx = r * 64 + ((s & 1) ? 60 : 3);
        }
        base[idx] = 0.0f;
    }
}

// ---------------------------------------------------------------------------
// ROI bilinear sampling (unchanged). S[b][c][r][p] == reference reshape quirk.
// ---------------------------------------------------------------------------
__global__ __launch_bounds__(256) void roi_k(const float* __restrict__ feat,
                                             const float* __restrict__ roi,
                                             float* __restrict__ S) {
    int b = blockIdx.x >> 5;
    int r = blockIdx.x & 31;
    const float* rr = roi + (size_t)(b * 32 + r) * 7;

    __shared__ int   offA[100], offB[100], offC[100], offD[100];
    __shared__ float wA[100], wB[100], wC[100], wD[100];

    int tid = threadIdx.x;
    if (tid < 100) {
        int i = tid / 10, j = tid % 10;
        float cx = rr[0], cy = rr[1];
        float W1 = rr[2], W2 = rr[3], H1 = rr[4], H2 = rr[5], psi = rr[6];
        float offx = ((float)j - 4.5f) / 10.0f;
        float offy = ((float)i - 4.5f) / 10.0f;
        float gx = offx * (W1 + W2) - (W1 - W2) * 0.5f;
        float gy = offy * (H1 + H2) - (H1 - H2) * 0.5f;
        float sn = sinf(psi), cs = cosf(psi);
        float xs = gx * cs + gy * sn + cx;
        float ys = -gx * sn + gy * cs + cy;

        float x0f = floorf(xs), y0f = floorf(ys);
        int x0 = (int)x0f, x1 = x0 + 1;
        int y0 = (int)y0f, y1 = y0 + 1;
        x0 = min(max(x0, 0), 55); x1 = min(max(x1, 0), 55);
        y0 = min(max(y0, 0), 55); y1 = min(max(y1, 0), 55);
        float fx0 = (float)x0, fx1 = (float)x1;
        float fy0 = (float)y0, fy1 = (float)y1;
        float step = (fx1 - fx0) * (fy1 - fy0);
        step = fminf(fmaxf(step, 0.001f), 2.0f);
        float inv = 1.0f / step;
        wA[tid] = (fx1 - xs) * (fy1 - ys) * inv;
        wB[tid] = (fx1 - xs) * (ys - fy0) * inv;
        wC[tid] = (xs - fx0) * (fy1 - ys) * inv;
        wD[tid] = (xs - fx0) * (ys - fy0) * inv;
        offA[tid] = y0 * 56 + x0;
        offB[tid] = y1 * 56 + x0;
        offC[tid] = y0 * 56 + x1;
        offD[tid] = y1 * 56 + x1;
    }
    __syncthreads();

    const float* __restrict__ fb = feat + (size_t)b * 128 * 3136;
    float* __restrict__ outb = S + ((size_t)b * 128 * 32 + r) * 100;
    int c = tid / 100;
    int p = tid - c * 100;
    for (int t = tid; t < 12800; t += 256) {
        const float* f = fb + c * 3136;
        float v = wA[p] * f[offA[p]] + wB[p] * f[offB[p]] +
                  wC[p] * f[offC[p]] + wD[p] * f[offD[p]];
        outb[(size_t)c * 3200 + p] = v;
        p += 56; c += 2;
        if (p >= 100) { p -= 100; ++c; }
    }
}

// ---------------------------------------------------------------------------
// FC split-K GEMM (unchanged from round 9): 128x128 tile, 8x8 micro, BK=16,
// ksplit=50, even/odd split layout, MINW=2.
// ---------------------------------------------------------------------------
__global__ __launch_bounds__(256, 2) void fc2_k(const float* __restrict__ A,
                                                const float* __restrict__ B,
                                                float* __restrict__ part) {
    constexpr int PAD = 132;
    __shared__ float sm[2 * 2 * 16 * PAD];

    const int tid = threadIdx.x;
    const int bn = blockIdx.x, bm = blockIdx.y, ks = blockIdx.z;
    const int tx = tid & 15, ty = tid >> 4;
    const int m0 = tid >> 2;
    const int kq = tid & 3;

    const int pc0 = (((m0 >> 2) & 1) * 16 + (m0 >> 3)) * 4 + (m0 & 3);

    const float* __restrict__ a0 = A + (size_t)(bm * 128 + m0) * 12800 + ks * 256 + kq * 4;
    const float* __restrict__ a1 = a0 + (size_t)64 * 12800;
    const float* __restrict__ b0 = B + (size_t)(bn * 128 + m0) * 12800 + ks * 256 + kq * 4;
    const float* __restrict__ b1 = b0 + (size_t)64 * 12800;

    float4 ar0 = *(const float4*)a0;
    float4 ar1 = *(const float4*)a1;
    float4 br0 = *(const float4*)b0;
    float4 br1 = *(const float4*)b1;

    float acc[8][8] = {};

    for (int it = 0; it < 16; ++it) {
        const int p = it & 1;
        float* __restrict__ As = sm + p * (2 * 16 * PAD);
        float* __restrict__ Ws = As + 16 * PAD;
        const int base = kq * 4 * PAD + pc0;
        As[base]                = ar0.x; As[base + PAD]          = ar0.y;
        As[base + 2 * PAD]      = ar0.z; As[base + 3 * PAD]      = ar0.w;
        As[base + 32]           = ar1.x; As[base + 32 + PAD]     = ar1.y;
        As[base + 32 + 2 * PAD] = ar1.z; As[base + 32 + 3 * PAD] = ar1.w;
        Ws[base]                = br0.x; Ws[base + PAD]          = br0.y;
        Ws[base + 2 * PAD]      = br0.z; Ws[base + 3 * PAD]      = br0.w;
        Ws[base + 32]           = br1.x; Ws[base + 32 + PAD]     = br1.y;
        Ws[base + 32 + 2 * PAD] = br1.z; Ws[base + 32 + 3 * PAD] = br1.w;
        __syncthreads();
        if (it + 1 < 16) {
            ar0 = *(const float4*)(a0 + (it + 1) * 16);
            ar1 = *(const float4*)(a1 + (it + 1) * 16);
            br0 = *(const float4*)(b0 + (it + 1) * 16);
            br1 = *(const float4*)(b1 + (it + 1) * 16);
        }
#pragma unroll
        for (int k = 0; k < 16; ++k) {
            float4 aL = *(const float4*)&As[k * PAD + ty * 4];
            float4 aH = *(const float4*)&As[k * PAD + 64 + ty * 4];
            float4 bL = *(const float4*)&Ws[k * PAD + tx * 4];
            float4 bH = *(const float4*)&Ws[k * PAD + 64 + tx * 4];
            float a[8] = {aL.x, aL.y, aL.z, aL.w, aH.x, aH.y, aH.z, aH.w};
            float b[8] = {bL.x, bL.y, bL.z, bL.w, bH.x, bH.y, bH.z, bH.w};
#pragma unroll
            for (int j = 0; j < 8; ++j)
#pragma unroll
                for (int i = 0; i < 8; ++i)
                    acc[j][i] += a[j] * b[i];
        }
    }

    float* __restrict__ po = part + (size_t)ks * 262144
                                  + (size_t)(bm * 128 + ty * 8) * 256 + bn * 128 + tx * 8;
#pragma unroll
    for (int j = 0; j < 8; ++j) {
        *(float4*)(po + (size_t)j * 256)     = make_float4(acc[j][0], acc[j][1], acc[j][2], acc[j][3]);
        *(float4*)(po + (size_t)j * 256 + 4) = make_float4(acc[j][4], acc[j][5], acc[j][6], acc[j][7]);
    }
}

__global__ __launch_bounds__(256) void fc2_reduce_k(const float* __restrict__ part,
                                                    const float* __restrict__ bias,
                                                    float* __restrict__ out) {
    int i = blockIdx.x * 256 + threadIdx.x;   // 0..262143
    float s = bias[i & 255];
    for (int ks = 0; ks < 50; ++ks) s += part[(size_t)ks * 262144 + i];
    out[i] = s;
}

// ---------------------------------------------------------------------------
extern "C" void kernel_launch(void* const* d_in, const int* in_sizes, int n_in,
                              void* d_out, int out_size, void* d_ws, size_t ws_size,
                              hipStream_t stream) {
    const float* x   = (const float*)d_in[0];
    const float* ROI = (const float*)d_in[1];
    const float* w1  = (const float*)d_in[2];
    const float* b1  = (const float*)d_in[3];
    const float* w2  = (const float*)d_in[4];
    const float* b2  = (const float*)d_in[5];
    const float* w3  = (const float*)d_in[6];
    const float* b3  = (const float*)d_in[7];
    const float* fcw = (const float*)d_in[8];
    const float* fcb = (const float*)d_in[9];
    float* out = (float*)d_out;

    char* ws = (char*)d_ws;
    // Workspace (peak ~117.8 MB, <= 128.45 MB proven safe):
    //  c1p  [0,           57,016,320)  conv1 -> conv2
    //  c2p  [57,016,320,  87,425,024)  conv2 -> conv3
    //  xpad [87,425,024, 107,386,880)  pad  -> conv1
    //  wT1/2/3 [107,386,880, 107,896,832)
    //  c3   [0,           51,380,224)  conv3 -> roi      (c1p dead)
    //  S    [57,016,320, 109,445,120)  roi -> fc         (c2p/xpad/wT dead)
    //  part [0,           52,428,800)  fc -> reduce      (c3 dead after roi)
    float* c1p  = (float*)(ws);
    float* c2p  = (float*)(ws + 57016320);
    float* xpad = (float*)(ws + 87425024);
    float* wT1  = (float*)(ws + 107386880);
    float* wT2  = (float*)(ws + 107397120);
    float* wT3  = (float*)(ws + 107601920);
    float* c3   = (float*)(ws);
    float* S    = (float*)(ws + 57016320);
    float* part = (float*)(ws);

    wtr_k<32,  75, 80 ><<<10,  256, 0, stream>>>(w1, wT1);
    wtr_k<64,  800, 800><<<200, 256, 0, stream>>>(w2, wT2);
    wtr_k<128, 576, 576><<<288, 256, 0, stream>>>(w3, wT3);
    pad_x_k<<<32 * 3 * 57, 256, 0, stream>>>(x, xpad);
    zb_c1p_k<<<1024, 256, 0, stream>>>(c1p);
    zb_c2p_k<<<2048, 64, 0, stream>>>(c2p);

    // conv1: 32co x 128px, 4x4 micro, 256 thr, BK=16, MINW=4 (unchanged cfg)
    conv_gemm_k<3, 2, 5, 5, 75, 80, 228, 228, 0, 112, 12544,
                32, 128, 4, 4, 116, 120, 2, 4, 4, 256, 16>
        <<<3136, 256, 0, stream>>>(xpad, wT1, b1, c1p);
    // conv2: 64co x 128px, 8x8 micro, 128-thread blocks (16x8 grid), BK=16
    conv_gemm_k<32, 2, 5, 5, 800, 800, 116, 120, 2, 56, 3136,
                64, 128, 8, 8, 58, 64, 1, 4, 2, 128, 16>
        <<<784, 128, 0, stream>>>(c1p, wT2, b2, c2p);
    // conv3: 128co x 128px, 8x8 micro, 256 thr, BK=32 (18 steps: half the
    // barrier drains; LDS 64KB -> 2 blocks/CU = what the reg bucket gives anyway)
    conv_gemm_k<64, 1, 3, 3, 576, 576, 58, 64, 3, 56, 3136,
                128, 128, 8, 8, 56, 56, 0, 0, 2, 256, 32>
        <<<784, 256, 0, stream>>>(c2p, wT3, b3, c3);

    // ROI sampling -> S[b][c][r][p]
    roi_k<<<1024, 256, 0, stream>>>(c3, ROI, S);
    // FC: split-K 50 + reduce
    fc2_k<<<dim3(2, 8, 50), 256, 0, stream>>>(S, fcw, part);
    fc2_reduce_k<<<1024, 256, 0, stream>>>(part, fcb, out);
}

// Round 11
// 724.204 us; speedup vs baseline: 1.1728x; 1.1728x over previous
//
#include <hip/hip_runtime.h>
#include <hip/hip_bf16.h>

#define LEAK 0.2f

__device__ __forceinline__ float lrelu(float a) { return a > 0.0f ? a : LEAK * a; }

// ---------------------------------------------------------------------------
// Implicit-GEMM conv + leaky ReLU.  out[co][pix] = sum_k wT[k][co]*B[k][pix]
// Micro-tile MR co x NR px. Double-buffered LDS, one barrier per BK-k step.
// NR==8: B stored with even/odd float4-group split (conflict-free reads).
// Register audit per config: acc(MR*NR) + staging(4*(BI... )) + addr must fit
// the 512/MINW wave bucket — violations spill to scratch (R6/R7/R10).
// ---------------------------------------------------------------------------
template<int CI, int ST, int KH, int KW, int KIN, int KP,
         int PIH, int PIW, int LP, int OW, int PPI,
         int CO, int NT, int MR, int NR, int OSH, int OSW, int OR0, int OC0,
         int MINW, int NTHR, int BK>
__global__ __launch_bounds__(NTHR, MINW) void conv_gemm_k(
    const float* __restrict__ in,    // padded input [img*CI + ci][PIH][PIW]
    const float* __restrict__ wT,    // [KP][CO]
    const float* __restrict__ bias,
    float* __restrict__ out)
{
    constexpr int KT  = KP / BK;
    constexpr int TXW = NT / 4;         // B staging pixel-quads per k-row
    constexpr int TXN = NT / NR;        // compute columns
    constexpr int BT  = BK * NT / 4;
    constexpr int AT  = BK * CO / 4;
    constexpr int BI  = (BT + NTHR - 1) / NTHR;
    constexpr int AI  = (AT + NTHR - 1) / NTHR;
    constexpr int ASZ = BK * CO;
    constexpr int BSZ = BK * NT;

    __shared__ float sm[2 * ASZ + 2 * BSZ];

    const int tid = threadIdx.x;
    const int bx  = blockIdx.x;
    const int tx  = tid % TXN;
    const int ty  = tid / TXN;

    // ---- per-thread staging geometry (K-independent) ----
    int bofs[BI], bkl[BI], bcol[BI];
#pragma unroll
    for (int q = 0; q < BI; ++q) {
        int task = tid + q * NTHR;
        if ((BT % NTHR == 0) || task < BT) {
            int kl  = task / TXW;
            int pxq = task % TXW;
            int px0 = bx * NT + pxq * 4;
            int img = px0 / PPI;
            int n   = px0 % PPI;
            int oh  = n / OW, ow = n % OW;
            bofs[q] = ((img * CI) * PIH + oh * ST) * PIW + ow * ST + LP;
            bkl[q]  = kl;
            // even/odd group split for NR==8 (conflict-free 8-wide reads)
            bcol[q] = (NR == 8) ? (((pxq & 1) * (TXW / 2) + (pxq >> 1)) * 4)
                                : (pxq * 4);
        }
    }

    float  br[BI][4];
    float4 ar[AI];

    auto gather = [&](int it) {
        int k0 = it * BK;
#pragma unroll
        for (int q = 0; q < BI; ++q) {
            int task = tid + q * NTHR;
            if ((BT % NTHR == 0) || task < BT) {
                int k = k0 + bkl[q];
                if (KP > KIN) k = min(k, KIN - 1);   // padded-K tail (weights 0)
                int ci  = k / (KH * KW);
                int rem = k - ci * (KH * KW);
                int kh  = rem / KW;
                int kw  = rem - kh * KW;
                const float* __restrict__ s = in + bofs[q] + (ci * PIH + kh) * PIW + kw;
                br[q][0] = s[0]; br[q][1] = s[ST]; br[q][2] = s[2 * ST]; br[q][3] = s[3 * ST];
            }
        }
#pragma unroll
        for (int p = 0; p < AI; ++p) {
            int task = tid + p * NTHR;
            if ((AT % NTHR == 0) || task < AT)
                ar[p] = *(const float4*)&wT[(size_t)k0 * CO + task * 4];
        }
    };

    float acc[MR][NR];
#pragma unroll
    for (int j = 0; j < MR; ++j) {
        float bv = bias[ty * MR + j];
#pragma unroll
        for (int i = 0; i < NR; ++i) acc[j][i] = bv;
    }

    gather(0);
    for (int it = 0; it < KT; ++it) {
        const int p = it & 1;
        float* __restrict__ Asb = sm + p * ASZ;
        float* __restrict__ Bsb = sm + 2 * ASZ + p * BSZ;
#pragma unroll
        for (int pa = 0; pa < AI; ++pa) {
            int task = tid + pa * NTHR;
            if ((AT % NTHR == 0) || task < AT)
                *(float4*)&Asb[task * 4] = ar[pa];
        }
#pragma unroll
        for (int q = 0; q < BI; ++q) {
            int task = tid + q * NTHR;
            if ((BT % NTHR == 0) || task < BT)
                *(float4*)&Bsb[bkl[q] * NT + bcol[q]] =
                    make_float4(br[q][0], br[q][1], br[q][2], br[q][3]);
        }
        __syncthreads();
        if (it + 1 < KT) gather(it + 1);
#pragma unroll
        for (int k = 0; k < BK; ++k) {
            float b[NR], a[MR];
            if (NR == 8) {
                // split layout: logical groups {2tx, 2tx+1} at {tx, NT/8+tx}
                *(float4*)&b[0] = *(const float4*)&Bsb[k * NT + tx * 4];
                *(float4*)&b[4] = *(const float4*)&Bsb[k * NT + NT / 2 + tx * 4];
            } else {
#pragma unroll
                for (int i = 0; i < NR / 4; ++i)
                    *(float4*)&b[4 * i] = *(const float4*)&Bsb[k * NT + tx * NR + 4 * i];
            }
#pragma unroll
            for (int j = 0; j < MR / 4; ++j)
                *(float4*)&a[4 * j] = *(const float4*)&Asb[k * CO + ty * MR + 4 * j];
#pragma unroll
            for (int j = 0; j < MR; ++j)
#pragma unroll
                for (int i = 0; i < NR; ++i)
                    acc[j][i] += a[j] * b[i];
        }
    }

    // ---- store (NR consecutive px share one row; OC0/ow 4-aligned) ----
    {
        int pxs = bx * NT + tx * NR;
        int img = pxs / PPI;
        int n   = pxs % PPI;
        int oh  = n / OW, ow = n % OW;
#pragma unroll
        for (int j = 0; j < MR; ++j) {
            int co = ty * MR + j;
            size_t off = (((size_t)img * CO + co) * OSH + (oh + OR0)) * OSW + (ow + OC0);
#pragma unroll
            for (int q = 0; q < NR / 4; ++q) {
                float4 v = make_float4(lrelu(acc[j][4 * q + 0]), lrelu(acc[j][4 * q + 1]),
                                       lrelu(acc[j][4 * q + 2]), lrelu(acc[j][4 * q + 3]));
                *(float4*)&out[off + 4 * q] = v;
            }
        }
    }
}

// ---------------------------------------------------------------------------
// Weight transpose: wT[k][co] = w[co][k], K padded to KP with zeros.
// ---------------------------------------------------------------------------
template<int CO, int KIN, int KP>
__global__ __launch_bounds__(256) void wtr_k(const float* __restrict__ w,
                                             float* __restrict__ wT) {
    int i = blockIdx.x * 256 + threadIdx.x;
    if (i >= KP * CO) return;
    int k = i / CO, co = i % CO;
    wT[i] = (k < KIN) ? w[(size_t)co * KIN + k] : 0.0f;
}

// ---------------------------------------------------------------------------
// x -> x_pad [32*3][228][228], 2-pixel zero border.
// ---------------------------------------------------------------------------
__global__ __launch_bounds__(256) void pad_x_k(const float* __restrict__ x,
                                               float* __restrict__ xp) {
    int blk = blockIdx.x;              // 32*3*57
    int r4 = blk % 57, ic = blk / 57;
    int wid = threadIdx.x >> 6, lane = threadIdx.x & 63;
    int row = r4 * 4 + wid;
    const float* __restrict__ src = x + (size_t)ic * 224 * 224 + (size_t)(row - 2) * 224;
    float* __restrict__ dst = xp + (size_t)ic * 228 * 228 + (size_t)row * 228;
    bool rok = (row >= 2) && (row < 226);
    for (int c = lane; c < 228; c += 64) {
        float v = 0.0f;
        if (rok && c >= 2 && c < 226) v = src[c - 2];
        dst[c] = v;
    }
}

// c1p plane = 116 x 120; data ow at layout col ow+4 (border cols 2,3,116,117).
__global__ __launch_bounds__(256) void zb_c1p_k(float* __restrict__ p) {
    float* base = p + (size_t)blockIdx.x * (116 * 120);
    for (int t = threadIdx.x; t < 928; t += 256) {
        int idx;
        if (t < 480) {
            int r = t / 120, c = t - r * 120;
            int row = (r < 2) ? r : r + 112;
            idx = row * 120 + c;
        } else {
            int s = t - 480;
            int r = s >> 2, c = s & 3;
            int col = (c < 2) ? (c + 2) : (c + 114);
            idx = (r + 2) * 120 + col;
        }
        base[idx] = 0.0f;
    }
}

// c2p plane = 58 x 64; data ow at layout col ow+4 (border cols 3,60).
__global__ __launch_bounds__(64) void zb_c2p_k(float* __restrict__ p) {
    float* base = p + (size_t)blockIdx.x * (58 * 64);
    for (int t = threadIdx.x; t < 240; t += 64) {
        int idx;
        if (t < 128) {
            int r = t >> 6, c = t & 63;
            idx = (r ? 57 : 0) * 64 + c;
        } else {
            int s = t - 128;
            int r = (s >> 1) + 1;
            idx = r * 64 + ((s & 1) ? 60 : 3);
        }
        base[idx] = 0.0f;
    }
}

// ---------------------------------------------------------------------------
// ROI bilinear sampling (unchanged). S[b][c][r][p] == reference reshape quirk.
// ---------------------------------------------------------------------------
__global__ __launch_bounds__(256) void roi_k(const float* __restrict__ feat,
                                             const float* __restrict__ roi,
                                             float* __restrict__ S) {
    int b = blockIdx.x >> 5;
    int r = blockIdx.x & 31;
    const float* rr = roi + (size_t)(b * 32 + r) * 7;

    __shared__ int   offA[100], offB[100], offC[100], offD[100];
    __shared__ float wA[100], wB[100], wC[100], wD[100];

    int tid = threadIdx.x;
    if (tid < 100) {
        int i = tid / 10, j = tid % 10;
        float cx = rr[0], cy = rr[1];
        float W1 = rr[2], W2 = rr[3], H1 = rr[4], H2 = rr[5], psi = rr[6];
        float offx = ((float)j - 4.5f) / 10.0f;
        float offy = ((float)i - 4.5f) / 10.0f;
        float gx = offx * (W1 + W2) - (W1 - W2) * 0.5f;
        float gy = offy * (H1 + H2) - (H1 - H2) * 0.5f;
        float sn = sinf(psi), cs = cosf(psi);
        float xs = gx * cs + gy * sn + cx;
        float ys = -gx * sn + gy * cs + cy;

        float x0f = floorf(xs), y0f = floorf(ys);
        int x0 = (int)x0f, x1 = x0 + 1;
        int y0 = (int)y0f, y1 = y0 + 1;
        x0 = min(max(x0, 0), 55); x1 = min(max(x1, 0), 55);
        y0 = min(max(y0, 0), 55); y1 = min(max(y1, 0), 55);
        float fx0 = (float)x0, fx1 = (float)x1;
        float fy0 = (float)y0, fy1 = (float)y1;
        float step = (fx1 - fx0) * (fy1 - fy0);
        step = fminf(fmaxf(step, 0.001f), 2.0f);
        float inv = 1.0f / step;
        wA[tid] = (fx1 - xs) * (fy1 - ys) * inv;
        wB[tid] = (fx1 - xs) * (ys - fy0) * inv;
        wC[tid] = (xs - fx0) * (fy1 - ys) * inv;
        wD[tid] = (xs - fx0) * (ys - fy0) * inv;
        offA[tid] = y0 * 56 + x0;
        offB[tid] = y1 * 56 + x0;
        offC[tid] = y0 * 56 + x1;
        offD[tid] = y1 * 56 + x1;
    }
    __syncthreads();

    const float* __restrict__ fb = feat + (size_t)b * 128 * 3136;
    float* __restrict__ outb = S + ((size_t)b * 128 * 32 + r) * 100;
    int c = tid / 100;
    int p = tid - c * 100;
    for (int t = tid; t < 12800; t += 256) {
        const float* f = fb + c * 3136;
        float v = wA[p] * f[offA[p]] + wB[p] * f[offB[p]] +
                  wC[p] * f[offC[p]] + wD[p] * f[offD[p]];
        outb[(size_t)c * 3200 + p] = v;
        p += 56; c += 2;
        if (p >= 100) { p -= 100; ++c; }
    }
}

// ---------------------------------------------------------------------------
// FC split-K GEMM v6: 128x128 tile, 8x8 micro, BK=16, ksplit=32
// (KSLICE=400 -> 25 steps). Grid (2, 8, 32) = 512 blocks = exactly
// 2 blocks/CU (round 9's 800-block grid was 3.125/CU imbalanced) and part
// traffic drops 52 -> 33.5 MB. Even/odd split layout, MINW=2 (no spill: R8).
// ---------------------------------------------------------------------------
__global__ __launch_bounds__(256, 2) void fc2_k(const float* __restrict__ A,
                                                const float* __restrict__ B,
                                                float* __restrict__ part) {
    constexpr int PAD = 132;
    __shared__ float sm[2 * 2 * 16 * PAD];

    const int tid = threadIdx.x;
    const int bn = blockIdx.x, bm = blockIdx.y, ks = blockIdx.z;
    const int tx = tid & 15, ty = tid >> 4;
    const int m0 = tid >> 2;
    const int kq = tid & 3;

    const int pc0 = (((m0 >> 2) & 1) * 16 + (m0 >> 3)) * 4 + (m0 & 3);

    const float* __restrict__ a0 = A + (size_t)(bm * 128 + m0) * 12800 + ks * 400 + kq * 4;
    const float* __restrict__ a1 = a0 + (size_t)64 * 12800;
    const float* __restrict__ b0 = B + (size_t)(bn * 128 + m0) * 12800 + ks * 400 + kq * 4;
    const float* __restrict__ b1 = b0 + (size_t)64 * 12800;

    float4 ar0 = *(const float4*)a0;
    float4 ar1 = *(const float4*)a1;
    float4 br0 = *(const float4*)b0;
    float4 br1 = *(const float4*)b1;

    float acc[8][8] = {};

    for (int it = 0; it < 25; ++it) {
        const int p = it & 1;
        float* __restrict__ As = sm + p * (2 * 16 * PAD);
        float* __restrict__ Ws = As + 16 * PAD;
        const int base = kq * 4 * PAD + pc0;
        As[base]                = ar0.x; As[base + PAD]          = ar0.y;
        As[base + 2 * PAD]      = ar0.z; As[base + 3 * PAD]      = ar0.w;
        As[base + 32]           = ar1.x; As[base + 32 + PAD]     = ar1.y;
        As[base + 32 + 2 * PAD] = ar1.z; As[base + 32 + 3 * PAD] = ar1.w;
        Ws[base]                = br0.x; Ws[base + PAD]          = br0.y;
        Ws[base + 2 * PAD]      = br0.z; Ws[base + 3 * PAD]      = br0.w;
        Ws[base + 32]           = br1.x; Ws[base + 32 + PAD]     = br1.y;
        Ws[base + 32 + 2 * PAD] = br1.z; Ws[base + 32 + 3 * PAD] = br1.w;
        __syncthreads();
        if (it + 1 < 25) {
            ar0 = *(const float4*)(a0 + (it + 1) * 16);
            ar1 = *(const float4*)(a1 + (it + 1) * 16);
            br0 = *(const float4*)(b0 + (it + 1) * 16);
            br1 = *(const float4*)(b1 + (it + 1) * 16);
        }
#pragma unroll
        for (int k = 0; k < 16; ++k) {
            float4 aL = *(const float4*)&As[k * PAD + ty * 4];
            float4 aH = *(const float4*)&As[k * PAD + 64 + ty * 4];
            float4 bL = *(const float4*)&Ws[k * PAD + tx * 4];
            float4 bH = *(const float4*)&Ws[k * PAD + 64 + tx * 4];
            float a[8] = {aL.x, aL.y, aL.z, aL.w, aH.x, aH.y, aH.z, aH.w};
            float b[8] = {bL.x, bL.y, bL.z, bL.w, bH.x, bH.y, bH.z, bH.w};
#pragma unroll
            for (int j = 0; j < 8; ++j)
#pragma unroll
                for (int i = 0; i < 8; ++i)
                    acc[j][i] += a[j] * b[i];
        }
    }

    float* __restrict__ po = part + (size_t)ks * 262144
                                  + (size_t)(bm * 128 + ty * 8) * 256 + bn * 128 + tx * 8;
#pragma unroll
    for (int j = 0; j < 8; ++j) {
        *(float4*)(po + (size_t)j * 256)     = make_float4(acc[j][0], acc[j][1], acc[j][2], acc[j][3]);
        *(float4*)(po + (size_t)j * 256 + 4) = make_float4(acc[j][4], acc[j][5], acc[j][6], acc[j][7]);
    }
}

__global__ __launch_bounds__(256) void fc2_reduce_k(const float* __restrict__ part,
                                                    const float* __restrict__ bias,
                                                    float* __restrict__ out) {
    int i = blockIdx.x * 256 + threadIdx.x;   // 0..262143
    float s = bias[i & 255];
    for (int ks = 0; ks < 32; ++ks) s += part[(size_t)ks * 262144 + i];
    out[i] = s;
}

// ---------------------------------------------------------------------------
extern "C" void kernel_launch(void* const* d_in, const int* in_sizes, int n_in,
                              void* d_out, int out_size, void* d_ws, size_t ws_size,
                              hipStream_t stream) {
    const float* x   = (const float*)d_in[0];
    const float* ROI = (const float*)d_in[1];
    const float* w1  = (const float*)d_in[2];
    const float* b1  = (const float*)d_in[3];
    const float* w2  = (const float*)d_in[4];
    const float* b2  = (const float*)d_in[5];
    const float* w3  = (const float*)d_in[6];
    const float* b3  = (const float*)d_in[7];
    const float* fcw = (const float*)d_in[8];
    const float* fcb = (const float*)d_in[9];
    float* out = (float*)d_out;

    char* ws = (char*)d_ws;
    // Workspace (peak ~117.8 MB, <= 128.45 MB proven safe):
    //  c1p  [0,           57,016,320)  conv1 -> conv2
    //  c2p  [57,016,320,  87,425,024)  conv2 -> conv3
    //  xpad [87,425,024, 107,386,880)  pad  -> conv1
    //  wT1/2/3 [107,386,880, 107,896,832)
    //  c3   [0,           51,380,224)  conv3 -> roi      (c1p dead)
    //  S    [57,016,320, 109,445,120)  roi -> fc         (c2p/xpad/wT dead)
    //  part [0,           33,554,432)  fc -> reduce      (c3 dead after roi)
    float* c1p  = (float*)(ws);
    float* c2p  = (float*)(ws + 57016320);
    float* xpad = (float*)(ws + 87425024);
    float* wT1  = (float*)(ws + 107386880);
    float* wT2  = (float*)(ws + 107397120);
    float* wT3  = (float*)(ws + 107601920);
    float* c3   = (float*)(ws);
    float* S    = (float*)(ws + 57016320);
    float* part = (float*)(ws);

    wtr_k<32,  75, 80 ><<<10,  256, 0, stream>>>(w1, wT1);
    wtr_k<64,  800, 800><<<200, 256, 0, stream>>>(w2, wT2);
    wtr_k<128, 576, 576><<<288, 256, 0, stream>>>(w3, wT3);
    pad_x_k<<<32 * 3 * 57, 256, 0, stream>>>(x, xpad);
    zb_c1p_k<<<1024, 256, 0, stream>>>(c1p);
    zb_c2p_k<<<2048, 64, 0, stream>>>(c2p);

    // conv1: 32co x 128px, 4x4 micro, 256 thr, BK=16, MINW=4 (R9 config)
    conv_gemm_k<3, 2, 5, 5, 75, 80, 228, 228, 0, 112, 12544,
                32, 128, 4, 4, 116, 120, 2, 4, 4, 256, 16>
        <<<3136, 256, 0, stream>>>(xpad, wT1, b1, c1p);
    // conv2: 64co x 128px, 8x4 micro, 256 thr, MINW=3 (R9 config)
    conv_gemm_k<32, 2, 5, 5, 800, 800, 116, 120, 2, 56, 3136,
                64, 128, 8, 4, 58, 64, 1, 4, 3, 256, 16>
        <<<784, 256, 0, stream>>>(c1p, wT2, b2, c2p);
    // conv3: 128co x 64px, 8x4 micro, grid 1568 = 6.1 blocks/CU
    // (R5-exact: measured 234 us, VGPR 48, zero conflicts — best known)
    conv_gemm_k<64, 1, 3, 3, 576, 576, 58, 64, 3, 56, 3136,
                128, 64, 8, 4, 56, 56, 0, 0, 4, 256, 16>
        <<<1568, 256, 0, stream>>>(c2p, wT3, b3, c3);

    // ROI sampling -> S[b][c][r][p]
    roi_k<<<1024, 256, 0, stream>>>(c3, ROI, S);
    // FC: split-K 32 + reduce
    fc2_k<<<dim3(2, 8, 32), 256, 0, stream>>>(S, fcw, part);
    fc2_reduce_k<<<1024, 256, 0, stream>>>(part, fcb, out);
}